// Round 10
// baseline (64.101 us; speedup 1.0000x reference)
//
#include <hip/hip_runtime.h>

// Depthwise 4x4 blur ([1/8,3/8,3/8,1/8] separable), stride 2, reflect-pad 1.
// x: [8,128,256,256] f32  ->  y: [8,128,128,128] f32
//
// Round-8 structure (62.3us, replay-safe): thread = 4 outcols x HP outrows,
// 32 contiguous lanes per row, 2 aligned float4 VMEM loads per row, halo
// via barrier-free intra-wave LDS exchange (per-threadIdx slots, same-wave
// ordering). Round-10 deltas: (1) HP 8 -> 16: strip halo overfetch drops
// 1.125x -> 1.0625x (~17 MB less HBM fetch); (2) non-temporal output
// stores via native ext_vector_type (r9: builtin rejects HIP_vector_type).
// History: LDS full staging 137us (r4), unaligned 16B 120us (r5), 16-lane
// tiles 117us (r6), edge loads 71.5us (r2/r7), __shfl 61.5us UNSAFE (r3),
// LDS exchange HP=8 62.3us (r8).

typedef float nf4 __attribute__((ext_vector_type(4)));

__global__ __launch_bounds__(256) void ds2d_kernel(const float* __restrict__ x,
                                                   float* __restrict__ y) {
    constexpr float k0 = 0.125f, k1 = 0.375f;
    constexpr int W  = 256;     // input width == height
    constexpr int OW = 128;     // output width == height
    constexpr int HP = 16;      // output rows per thread

    __shared__ float2 buf[256]; // per-thread exchange slot: {f1.w, f0.x}

    const int tid = blockIdx.x * 256 + threadIdx.x;
    const int t   = tid & 31;           // col-quad within output row (128/4)
    const int s   = (tid >> 5) & 7;     // row strip (128/16)
    const int nc  = tid >> 8;           // fused N*C plane (8*128 = 1024)
    const int cb  = t << 3;             // leftmost input col = 8t
    const int oh0 = s * HP;

    const float* __restrict__ base = x + (size_t)nc * (W * W);
    float* __restrict__ out = y + ((size_t)nc * OW + oh0) * OW + (t << 2);

    const bool e0  = (t == 0);
    const bool e31 = (t == 31);
    const int  lx  = threadIdx.x;
    const int  im  = e0  ? lx : lx - 1;  // left neighbor slot (edge: own, unused)
    const int  ip  = e31 ? lx : lx + 1;  // right neighbor slot

    const int row0 = oh0 * 2 - 1;       // first input row of this strip

    float acc[2][4];                    // rotating accumulators, parity = m&1
    #pragma unroll
    for (int p = 0; p < 2; ++p)
        #pragma unroll
        for (int c = 0; c < 4; ++c) acc[p][c] = 0.f;

    #pragma unroll
    for (int rl = 0; rl < 2 * HP + 2; ++rl) {      // 34 input rows
        int r = row0 + rl;
        r = (r < 0) ? -r : ((r > W - 1) ? 2 * W - 2 - r : r);
        const float* __restrict__ row = base + (r << 8);

        const float4 f0 = *reinterpret_cast<const float4*>(row + cb);
        const float4 f1 = *reinterpret_cast<const float4*>(row + cb + 4);

        // intra-wave halo exchange through LDS (no barrier: same-wave order)
        buf[lx] = make_float2(f1.w, f0.x);
        const float a_n = buf[im].x;     // lane t-1's f1.w == row[cb-1]
        const float d_n = buf[ip].y;     // lane t+1's f0.x == row[cb+8]
        const float a = e0  ? f0.y : a_n;   // reflect: col -1  -> col 1
        const float d = e31 ? f1.z : d_n;   // reflect: col 256 -> col 254

        // horizontal 4-tap at the 4 output positions (computed once per row)
        const float h0 = k0 * (a    + f0.z) + k1 * (f0.x + f0.y);
        const float h1 = k0 * (f0.y + f1.x) + k1 * (f0.z + f0.w);
        const float h2 = k0 * (f0.w + f1.z) + k1 * (f1.x + f1.y);
        const float h3 = k0 * (f1.y + d   ) + k1 * (f1.z + f1.w);

        // output row m uses input rows rl = 2m..2m+3, weights [k0,k1,k1,k0]
        const int  m   = rl >> 1;
        const bool odd = (rl & 1) != 0;
        if (!odd) {
            if (m >= 1) {               // row m-1, weight k1
                float* Aa = acc[(m - 1) & 1];
                Aa[0] += k1 * h0; Aa[1] += k1 * h1; Aa[2] += k1 * h2; Aa[3] += k1 * h3;
            }
            if (m <= HP - 1) {          // row m, weight k0 (first touch)
                float* Aa = acc[m & 1];
                Aa[0] = k0 * h0; Aa[1] = k0 * h1; Aa[2] = k0 * h2; Aa[3] = k0 * h3;
            }
        } else {
            if (m >= 1) {               // row m-1, weight k0 -> row done
                float* Aa = acc[(m - 1) & 1];
                Aa[0] += k0 * h0; Aa[1] += k0 * h1; Aa[2] += k0 * h2; Aa[3] += k0 * h3;
                nf4 o; o.x = Aa[0]; o.y = Aa[1]; o.z = Aa[2]; o.w = Aa[3];
                __builtin_nontemporal_store(
                    o, reinterpret_cast<nf4*>(out + (size_t)(m - 1) * OW));
            }
            if (m <= HP - 1) {          // row m, weight k1
                float* Aa = acc[m & 1];
                Aa[0] += k1 * h0; Aa[1] += k1 * h1; Aa[2] += k1 * h2; Aa[3] += k1 * h3;
            }
        }
    }
}

extern "C" void kernel_launch(void* const* d_in, const int* in_sizes, int n_in,
                              void* d_out, int out_size, void* d_ws, size_t ws_size,
                              hipStream_t stream) {
    const float* x = (const float*)d_in[0];
    float* y = (float*)d_out;

    // 1024 planes * 8 strips * 32 col-quads = 262,144 threads, exact
    const int block = 256;
    const int grid = (1024 * 8 * 32) / block;   // 1024
    ds2d_kernel<<<grid, block, 0, stream>>>(x, y);
}

// Round 11
// 57.850 us; speedup vs baseline: 1.1081x; 1.1081x over previous
//
#include <hip/hip_runtime.h>

// Depthwise 4x4 blur ([1/8,3/8,3/8,1/8] separable), stride 2, reflect-pad 1.
// x: [8,128,256,256] f32  ->  y: [8,128,128,128] f32
//
// Round-8 structure EXACTLY (62.3us, replay-safe, max occupancy 32 waves/CU):
// thread = 4 outcols x 8 outrows, 32 contiguous lanes per row, 2 aligned
// float4 loads per row, halo via barrier-free intra-wave LDS exchange.
// Round-11 single delta: non-temporal output stores (output is never
// re-read; keep it out of L1/L2 so input/halo lines survive).
// History: LDS full staging 137us (r4), unaligned 16B 120us (r5), 16-lane
// tiles 117us (r6), edge loads 71.5us (r2/r7), __shfl 61.5us UNSAFE (r3),
// LDS exchange HP=8 62.3us (r8), HP=16+NT 64.1us (r10: TLP halved, bad).

typedef float nf4 __attribute__((ext_vector_type(4)));

__global__ __launch_bounds__(256) void ds2d_kernel(const float* __restrict__ x,
                                                   float* __restrict__ y) {
    constexpr float k0 = 0.125f, k1 = 0.375f;
    constexpr int W  = 256;     // input width == height
    constexpr int OW = 128;     // output width == height
    constexpr int HP = 8;       // output rows per thread

    __shared__ float2 buf[256]; // per-thread exchange slot: {f1.w, f0.x}

    const int tid = blockIdx.x * 256 + threadIdx.x;
    const int t   = tid & 31;           // col-quad within output row (128/4)
    const int s   = (tid >> 5) & 15;    // row strip (128/8)
    const int nc  = tid >> 9;           // fused N*C plane (8*128 = 1024)
    const int cb  = t << 3;             // leftmost input col = 8t
    const int oh0 = s * HP;

    const float* __restrict__ base = x + (size_t)nc * (W * W);
    float* __restrict__ out = y + ((size_t)nc * OW + oh0) * OW + (t << 2);

    const bool e0  = (t == 0);
    const bool e31 = (t == 31);
    const int  lx  = threadIdx.x;
    const int  im  = e0  ? lx : lx - 1;  // left neighbor slot (edge: own, unused)
    const int  ip  = e31 ? lx : lx + 1;  // right neighbor slot

    const int row0 = oh0 * 2 - 1;       // first input row of this strip

    float acc[2][4];                    // rotating accumulators, parity = m&1
    #pragma unroll
    for (int p = 0; p < 2; ++p)
        #pragma unroll
        for (int c = 0; c < 4; ++c) acc[p][c] = 0.f;

    #pragma unroll
    for (int rl = 0; rl < 2 * HP + 2; ++rl) {      // 18 input rows
        int r = row0 + rl;
        r = (r < 0) ? -r : ((r > W - 1) ? 2 * W - 2 - r : r);
        const float* __restrict__ row = base + (r << 8);

        const float4 f0 = *reinterpret_cast<const float4*>(row + cb);
        const float4 f1 = *reinterpret_cast<const float4*>(row + cb + 4);

        // intra-wave halo exchange through LDS (no barrier: same-wave order)
        buf[lx] = make_float2(f1.w, f0.x);
        const float a_n = buf[im].x;     // lane t-1's f1.w == row[cb-1]
        const float d_n = buf[ip].y;     // lane t+1's f0.x == row[cb+8]
        const float a = e0  ? f0.y : a_n;   // reflect: col -1  -> col 1
        const float d = e31 ? f1.z : d_n;   // reflect: col 256 -> col 254

        // horizontal 4-tap at the 4 output positions (computed once per row)
        const float h0 = k0 * (a    + f0.z) + k1 * (f0.x + f0.y);
        const float h1 = k0 * (f0.y + f1.x) + k1 * (f0.z + f0.w);
        const float h2 = k0 * (f0.w + f1.z) + k1 * (f1.x + f1.y);
        const float h3 = k0 * (f1.y + d   ) + k1 * (f1.z + f1.w);

        // output row m uses input rows rl = 2m..2m+3, weights [k0,k1,k1,k0]
        const int  m   = rl >> 1;
        const bool odd = (rl & 1) != 0;
        if (!odd) {
            if (m >= 1) {               // row m-1, weight k1
                float* Aa = acc[(m - 1) & 1];
                Aa[0] += k1 * h0; Aa[1] += k1 * h1; Aa[2] += k1 * h2; Aa[3] += k1 * h3;
            }
            if (m <= HP - 1) {          // row m, weight k0 (first touch)
                float* Aa = acc[m & 1];
                Aa[0] = k0 * h0; Aa[1] = k0 * h1; Aa[2] = k0 * h2; Aa[3] = k0 * h3;
            }
        } else {
            if (m >= 1) {               // row m-1, weight k0 -> row done
                float* Aa = acc[(m - 1) & 1];
                Aa[0] += k0 * h0; Aa[1] += k0 * h1; Aa[2] += k0 * h2; Aa[3] += k0 * h3;
                nf4 o; o.x = Aa[0]; o.y = Aa[1]; o.z = Aa[2]; o.w = Aa[3];
                __builtin_nontemporal_store(
                    o, reinterpret_cast<nf4*>(out + (size_t)(m - 1) * OW));
            }
            if (m <= HP - 1) {          // row m, weight k1
                float* Aa = acc[m & 1];
                Aa[0] += k1 * h0; Aa[1] += k1 * h1; Aa[2] += k1 * h2; Aa[3] += k1 * h3;
            }
        }
    }
}

extern "C" void kernel_launch(void* const* d_in, const int* in_sizes, int n_in,
                              void* d_out, int out_size, void* d_ws, size_t ws_size,
                              hipStream_t stream) {
    const float* x = (const float*)d_in[0];
    float* y = (float*)d_out;

    // 1024 planes * 16 strips * 32 col-quads = 524,288 threads, exact
    const int block = 256;
    const int grid = (1024 * 16 * 32) / block;   // 2048
    ds2d_kernel<<<grid, block, 0, stream>>>(x, y);
}